// Round 4
// baseline (472.558 us; speedup 1.0000x reference)
//
#include <hip/hip_runtime.h>

#define B_   32
#define S_   8192
#define C_   256   // KD == QD == 256
#define LD_  256
#define H_   8
#define SD_  32
#define NCH  32    // chunks per batch
#define CH   256   // keys per chunk (== blockDim)

// workspace layout (floats)
#define WS_QK    0
#define WS_LSUM  (WS_QK + B_*H_*C_)
#define WS_CTX   (WS_LSUM + B_*H_)
#define WS_TOTAL (WS_CTX + B_*H_*C_)

// ---------------------------------------------------------------------------
// Kernel A: qk[b,h,c] = (1/sqrt(SD)) * sum_d (query[b]·Wq)[h*SD+d] * Wk[h*SD+d, c]
// ---------------------------------------------------------------------------
__global__ __launch_bounds__(256) void proj_qk(const float* __restrict__ query,
                                               const float* __restrict__ Wq,
                                               const float* __restrict__ Wk,
                                               float* __restrict__ ws) {
    const int b = blockIdx.x, t = threadIdx.x;
    __shared__ float qry[C_];
    __shared__ float qv[LD_];
    qry[t] = query[b * C_ + t];
    __syncthreads();
    // q[l] = sum_c qry[c] * Wq[l, c]   (thread t owns l = t)
    {
        const float* wr = Wq + t * C_;
        float a = 0.f;
        for (int c = 0; c < C_; c += 4) {
            float4 w = *(const float4*)(wr + c);
            float4 x = *(const float4*)(qry + c);
            a = fmaf(w.x, x.x, fmaf(w.y, x.y, fmaf(w.z, x.z, fmaf(w.w, x.w, a))));
        }
        qv[t] = a;
    }
    __syncthreads();
    // qk[h][c] for c = t; static head loop (avoid runtime-indexed reg array)
    const float scale = 0.17677669529663687f;  // 1/sqrt(32)
    float* qkb = ws + WS_QK + b * H_ * C_;
    #pragma unroll
    for (int h = 0; h < H_; h++) {
        float a = 0.f;
        #pragma unroll 8
        for (int d = 0; d < SD_; d++) {
            a = fmaf(qv[h * SD_ + d], Wk[(h * SD_ + d) * C_ + t], a);
        }
        qkb[h * C_ + t] = a * scale;
    }
}

// ---------------------------------------------------------------------------
// Kernel B: per (b, chunk): dot -> unmasked out, p=exp(masked), partial l and
// ctx[h][c] accumulated into global via atomics (no max subtraction needed:
// dot ~ N(0,1), |dot| < ~8 so exp() is fp32-safe; masked-out lanes exp(-1e4)=0)
// Phase 3 re-reads the block's own 256KB chunk right after phase 1 fetched it.
// Eviction-distance model: co-resident blocks (~1024) x 256KB ~ L3 capacity ->
// phase-3 L3 hit rate uncertain; FETCH_SIZE on first bench is the decision
// point for switching to the LDS-staged single-read variant (held in reserve).
// ---------------------------------------------------------------------------
__global__ __launch_bounds__(256) void attn_pass(const float* __restrict__ keys,
                                                 const float* __restrict__ pmask,
                                                 const float* __restrict__ ws_qk,
                                                 float* __restrict__ lsum,
                                                 float* __restrict__ ctxsum,
                                                 float* __restrict__ out_unmasked) {
    const int b = blockIdx.y, ch = blockIdx.x, t = threadIdx.x;
    const int s0 = ch * CH;
    __shared__ float qk_s[H_ * C_];   // [h][c]
    __shared__ float p_s[CH][H_];     // [s_local][h], rows 32B-aligned
    __shared__ float red[256];

    // mask value hoisted so it overlaps the FMA chain; read-once -> nontemporal
    const float pm  = __builtin_nontemporal_load(pmask + b * S_ + s0 + t);

    const float* qkb = ws_qk + b * H_ * C_;
    for (int i = t; i < H_ * C_; i += 256) qk_s[i] = qkb[i];
    __syncthreads();

    // ---- phase 1: thread t owns key s0+t; dot over 256 channels, 8 heads ----
    const float* krow = keys + ((size_t)(b * S_) + s0 + t) * C_;
    float acc0 = 0.f, acc1 = 0.f, acc2 = 0.f, acc3 = 0.f;
    float acc4 = 0.f, acc5 = 0.f, acc6 = 0.f, acc7 = 0.f;
    for (int c = 0; c < C_; c += 4) {
        float4 kv = *(const float4*)(krow + c);
        float4 w0 = *(const float4*)(qk_s + 0 * C_ + c);
        float4 w1 = *(const float4*)(qk_s + 1 * C_ + c);
        float4 w2 = *(const float4*)(qk_s + 2 * C_ + c);
        float4 w3 = *(const float4*)(qk_s + 3 * C_ + c);
        float4 w4 = *(const float4*)(qk_s + 4 * C_ + c);
        float4 w5 = *(const float4*)(qk_s + 5 * C_ + c);
        float4 w6 = *(const float4*)(qk_s + 6 * C_ + c);
        float4 w7 = *(const float4*)(qk_s + 7 * C_ + c);
        acc0 = fmaf(kv.x, w0.x, fmaf(kv.y, w0.y, fmaf(kv.z, w0.z, fmaf(kv.w, w0.w, acc0))));
        acc1 = fmaf(kv.x, w1.x, fmaf(kv.y, w1.y, fmaf(kv.z, w1.z, fmaf(kv.w, w1.w, acc1))));
        acc2 = fmaf(kv.x, w2.x, fmaf(kv.y, w2.y, fmaf(kv.z, w2.z, fmaf(kv.w, w2.w, acc2))));
        acc3 = fmaf(kv.x, w3.x, fmaf(kv.y, w3.y, fmaf(kv.z, w3.z, fmaf(kv.w, w3.w, acc3))));
        acc4 = fmaf(kv.x, w4.x, fmaf(kv.y, w4.y, fmaf(kv.z, w4.z, fmaf(kv.w, w4.w, acc4))));
        acc5 = fmaf(kv.x, w5.x, fmaf(kv.y, w5.y, fmaf(kv.z, w5.z, fmaf(kv.w, w5.w, acc5))));
        acc6 = fmaf(kv.x, w6.x, fmaf(kv.y, w6.y, fmaf(kv.z, w6.z, fmaf(kv.w, w6.w, acc6))));
        acc7 = fmaf(kv.x, w7.x, fmaf(kv.y, w7.y, fmaf(kv.z, w7.z, fmaf(kv.w, w7.w, acc7))));
    }
    // unmasked output: non-temporal (write-once stream; keep keys in L2/L3)
    float* ub = out_unmasked + (size_t)b * H_ * S_ + s0 + t;
    __builtin_nontemporal_store(acc0, ub + 0 * S_);
    __builtin_nontemporal_store(acc1, ub + 1 * S_);
    __builtin_nontemporal_store(acc2, ub + 2 * S_);
    __builtin_nontemporal_store(acc3, ub + 3 * S_);
    __builtin_nontemporal_store(acc4, ub + 4 * S_);
    __builtin_nontemporal_store(acc5, ub + 5 * S_);
    __builtin_nontemporal_store(acc6, ub + 6 * S_);
    __builtin_nontemporal_store(acc7, ub + 7 * S_);
    // mask + exp -> p
    const float pen = (1.0f - pm) * -10000.0f;
    float4 pv0 = make_float4(__expf(acc0 + pen), __expf(acc1 + pen),
                             __expf(acc2 + pen), __expf(acc3 + pen));
    float4 pv1 = make_float4(__expf(acc4 + pen), __expf(acc5 + pen),
                             __expf(acc6 + pen), __expf(acc7 + pen));
    *(float4*)&p_s[t][0] = pv0;
    *(float4*)&p_s[t][4] = pv1;
    __syncthreads();

    // ---- per-head p sums (two-stage) ----
    {
        const int h = t & 7, idx = t >> 3;
        float part = 0.f;
        #pragma unroll
        for (int i = 0; i < CH / 32; i++) part += p_s[idx + i * 32][h];
        red[t] = part;  // bank = t%32: conflict-free
    }
    __syncthreads();
    if (t < H_) {
        float tot = 0.f;
        #pragma unroll 8
        for (int idx = 0; idx < 32; idx++) tot += red[idx * 8 + t];
        atomicAdd(&lsum[b * H_ + t], tot);
    }

    // ---- phase 3: ctx[h][c=t] += sum_s p[h][s]*keys[s][c]; reverse s for LIFO
    float f0 = 0.f, f1 = 0.f, f2 = 0.f, f3 = 0.f, f4 = 0.f, f5 = 0.f, f6 = 0.f, f7 = 0.f;
    const float* kcol = keys + ((size_t)(b * S_) + s0) * C_ + t;
    #pragma unroll 8
    for (int s = CH - 1; s >= 0; s--) {
        float kv = kcol[(size_t)s * C_];          // coalesced across threads
        float4 p0 = *(const float4*)&p_s[s][0];   // LDS broadcast
        float4 p1 = *(const float4*)&p_s[s][4];
        f0 = fmaf(p0.x, kv, f0); f1 = fmaf(p0.y, kv, f1);
        f2 = fmaf(p0.z, kv, f2); f3 = fmaf(p0.w, kv, f3);
        f4 = fmaf(p1.x, kv, f4); f5 = fmaf(p1.y, kv, f5);
        f6 = fmaf(p1.z, kv, f6); f7 = fmaf(p1.w, kv, f7);
    }
    float* cb = ctxsum + (size_t)b * H_ * C_ + t;
    atomicAdd(cb + 0 * C_, f0); atomicAdd(cb + 1 * C_, f1);
    atomicAdd(cb + 2 * C_, f2); atomicAdd(cb + 3 * C_, f3);
    atomicAdd(cb + 4 * C_, f4); atomicAdd(cb + 5 * C_, f5);
    atomicAdd(cb + 6 * C_, f6); atomicAdd(cb + 7 * C_, f7);
}

// ---------------------------------------------------------------------------
// Kernel C: ctxn = ctx/L; out[l] = Wv[l,:]·ctxn[h(l),:]; unified = Wu·out + bu
// ---------------------------------------------------------------------------
__global__ __launch_bounds__(256) void finalize(const float* __restrict__ Wv,
                                                const float* __restrict__ Wu,
                                                const float* __restrict__ bu,
                                                const float* __restrict__ lsum,
                                                const float* __restrict__ ctxsum,
                                                float* __restrict__ out_unified) {
    const int b = blockIdx.x, t = threadIdx.x;
    __shared__ float ctxn[H_ * C_];
    __shared__ float outv[LD_];
    __shared__ float linv[H_];
    if (t < H_) linv[t] = 1.0f / lsum[b * H_ + t];
    __syncthreads();
    for (int i = t; i < H_ * C_; i += 256)
        ctxn[i] = ctxsum[(size_t)b * H_ * C_ + i] * linv[i >> 8];
    __syncthreads();
    {
        const float* wr = Wv + t * C_;
        const float* cx = ctxn + (t >> 5) * C_;
        float a = 0.f;
        for (int c = 0; c < C_; c += 4) {
            float4 w = *(const float4*)(wr + c);
            float4 x = *(const float4*)(cx + c);
            a = fmaf(w.x, x.x, fmaf(w.y, x.y, fmaf(w.z, x.z, fmaf(w.w, x.w, a))));
        }
        outv[t] = a;
    }
    __syncthreads();
    {
        const float* wr = Wu + t * C_;
        float a = bu[t];
        for (int c = 0; c < C_; c += 4) {
            float4 w = *(const float4*)(wr + c);
            float4 x = *(const float4*)(outv + c);
            a = fmaf(w.x, x.x, fmaf(w.y, x.y, fmaf(w.z, x.z, fmaf(w.w, x.w, a))));
        }
        out_unified[b * LD_ + t] = a;
    }
}

extern "C" void kernel_launch(void* const* d_in, const int* in_sizes, int n_in,
                              void* d_out, int out_size, void* d_ws, size_t ws_size,
                              hipStream_t stream) {
    const float* query = (const float*)d_in[0];
    const float* keys  = (const float*)d_in[1];
    const float* pmask = (const float*)d_in[2];
    const float* Wq    = (const float*)d_in[3];
    const float* Wk    = (const float*)d_in[4];
    const float* Wv    = (const float*)d_in[5];
    const float* Wu    = (const float*)d_in[6];
    const float* bu    = (const float*)d_in[7];

    float* out          = (float*)d_out;
    float* out_unified  = out;              // 32*256 floats
    float* out_unmasked = out + B_ * LD_;   // 32*8*8192 floats
    float* ws           = (float*)d_ws;

    // zero the accumulators (ws is re-poisoned to 0xAA before every launch)
    hipMemsetAsync(ws + WS_LSUM, 0, (size_t)(B_ * H_ + B_ * H_ * C_) * sizeof(float), stream);

    proj_qk<<<B_, 256, 0, stream>>>(query, Wq, Wk, ws);

    dim3 gridB(NCH, B_);
    attn_pass<<<gridB, 256, 0, stream>>>(keys, pmask, ws + WS_QK,
                                         ws + WS_LSUM, ws + WS_CTX, out_unmasked);

    finalize<<<B_, 256, 0, stream>>>(Wv, Wu, bu, ws + WS_LSUM, ws + WS_CTX, out_unified);
}